// Round 9
// baseline (345.342 us; speedup 1.0000x reference)
//
#include <hip/hip_runtime.h>
#include <math.h>

#define EMBED 1024
#define HEADS 16
#define HD    64
#define SEQ   2048
#define BATCH 4
#define ROWS  (BATCH * SEQ)   // 8192

typedef _Float16 f16;
typedef __attribute__((ext_vector_type(8))) _Float16 f16x8;
typedef __attribute__((ext_vector_type(4))) _Float16 f16x4;
typedef __attribute__((ext_vector_type(2))) _Float16 f16x2;
typedef __attribute__((ext_vector_type(4))) float    fx4;

typedef __attribute__((address_space(3))) char  lds_char;
typedef __attribute__((address_space(1))) const char glb_char;

#define SCALE_Q 0.18033688011112042f   // 0.125 * log2(e), folded into Q at GEMM1

// Raw barrier + counted waits (GEMM): __syncthreads() emits vmcnt(0) and
// would drain the stage-ahead pipeline every tile.
#define BAR_LGKM()  asm volatile("s_waitcnt lgkmcnt(0)\n\ts_barrier" ::: "memory")
#define BAR_VM8()   asm volatile("s_waitcnt vmcnt(8)\n\ts_barrier" ::: "memory")
#define BAR_VM0()   asm volatile("s_waitcnt vmcnt(0)\n\ts_barrier" ::: "memory")

// ---------------------------------------------------------------------------
// Fused prep (unchanged).
// ---------------------------------------------------------------------------
__global__ __launch_bounds__(256) void prep(const float* __restrict__ x,
                                            f16* __restrict__ x_h,
                                            const float* __restrict__ Wqkv,
                                            f16* __restrict__ Wqt,
                                            const float* __restrict__ Wproj,
                                            f16* __restrict__ Wpt) {
    const int blk = blockIdx.x;
    if (blk < 8192) {
        const int i = (blk * 256 + threadIdx.x) * 4;
        const float4 v = *(const float4*)(x + i);
        f16x4 o = {(f16)v.x, (f16)v.y, (f16)v.z, (f16)v.w};
        *(f16x4*)(x_h + i) = o;
        return;
    }
    __shared__ float t[32][33];
    const float* W;
    f16* Wt;
    int N, bx, by;
    if (blk < 8192 + 3072) {
        const int b2 = blk - 8192;
        W = Wqkv; Wt = Wqt; N = 3072; bx = b2 % 96; by = b2 / 96;
    } else {
        const int b2 = blk - 8192 - 3072;
        W = Wproj; Wt = Wpt; N = 1024; bx = b2 % 32; by = b2 / 32;
    }
    const int tx = threadIdx.x & 31, ty = threadIdx.x >> 5;   // 32 x 8
    const int k0 = by * 32, n0 = bx * 32;
    #pragma unroll
    for (int i = 0; i < 4; i++)
        t[ty + i * 8][tx] = W[(size_t)(k0 + ty + i * 8) * N + n0 + tx];
    __syncthreads();
    #pragma unroll
    for (int i = 0; i < 4; i++)
        Wt[(size_t)(n0 + ty + i * 8) * 1024 + k0 + tx] = (f16)t[tx][ty + i * 8];
}

// ---------------------------------------------------------------------------
// f16 MFMA GEMM v4 (unchanged from round 8): counted-vmcnt double-buffered
// pipeline (T3+T4). Per iter: ds_read 16 frags -> lgkmcnt(0)+barrier (NO vm
// drain) -> STAGE(t+2) -> 32 MFMA -> vmcnt(8)+barrier. BK=64 + chunk-XOR
// swizzle; BM=128 both modes; 64 KB LDS -> 2 blocks/CU.
// ---------------------------------------------------------------------------
template <int MODE>
__global__ __launch_bounds__(256) void gemm_f16k(const f16* __restrict__ A,
                                                 const f16* __restrict__ Bt,
                                                 const float* __restrict__ bias,
                                                 float* __restrict__ Cf,
                                                 f16* __restrict__ qH,
                                                 f16* __restrict__ kH,
                                                 f16* __restrict__ vT,
                                                 int M, int N, int K) {
    constexpr int TEL = 128 * 64;                       // f16 per buffer
    __shared__ alignas(16) f16 smem[4 * TEL];           // 64 KB

    f16 (*As0)[64] = (f16(*)[64])(smem);
    f16 (*As1)[64] = (f16(*)[64])(smem + TEL);
    f16 (*Bs0)[64] = (f16(*)[64])(smem + 2 * TEL);
    f16 (*Bs1)[64] = (f16(*)[64])(smem + 3 * TEL);
    lds_char* a0b = (lds_char*)smem;
    lds_char* a1b = (lds_char*)smem + 2 * TEL;          // bytes
    lds_char* b0b = (lds_char*)smem + 4 * TEL;
    lds_char* b1b = (lds_char*)smem + 6 * TEL;

    const int tid  = threadIdx.x;
    const int wave = tid >> 6;
    const int lane = tid & 63;
    const int quad = lane >> 4;
    const int l16  = lane & 15;

    const int nwg  = gridDim.x * gridDim.y;
    const int flat = blockIdx.y * gridDim.x + blockIdx.x;
    const int swz  = (flat & 7) * (nwg >> 3) + (flat >> 3);
    const int bx   = swz % gridDim.x;
    const int by   = swz / gridDim.x;
    const int m0   = by * 128;
    const int n0   = bx * 128;
    const int wm   = wave & 1;
    const int wn   = wave >> 1;

    fx4 acc[4][4];
    #pragma unroll
    for (int i = 0; i < 4; i++)
        #pragma unroll
        for (int j = 0; j < 4; j++)
            acc[i][j] = (fx4){0.f, 0.f, 0.f, 0.f};

    const int srow = lane >> 3;
    const int sjl  = ((lane & 7) ^ (srow & 7)) * 8;     // f16 offset
    auto STAGE = [&](lds_char* asb, lds_char* bsb, int k0) {   // 8 VMEM/wave
        #pragma unroll
        for (int it = 0; it < 4; it++) {
            const int g = it * 4 + wave;
            const int r = g * 8 + srow;
            __builtin_amdgcn_global_load_lds(
                (glb_char*)(A + (size_t)(m0 + r) * K + k0 + sjl),
                asb + g * 1024, 16, 0, 0);
            __builtin_amdgcn_global_load_lds(
                (glb_char*)(Bt + (size_t)(n0 + r) * K + k0 + sjl),
                bsb + g * 1024, 16, 0, 0);
        }
    };

    const int NT = K >> 6;   // 16

    auto ITER = [&](f16 (*As)[64], f16 (*Bs)[64],
                    lds_char* asb, lds_char* bsb, int t) {
        f16x8 af0[4], af1[4], bf0[4], bf1[4];
        #pragma unroll
        for (int i = 0; i < 4; i++) {
            const int ra = wm * 64 + i * 16 + l16;
            const int rb = wn * 64 + i * 16 + l16;
            af0[i] = *(const f16x8*)&As[ra][((0 + quad) ^ (ra & 7)) * 8];
            af1[i] = *(const f16x8*)&As[ra][((4 + quad) ^ (ra & 7)) * 8];
            bf0[i] = *(const f16x8*)&Bs[rb][((0 + quad) ^ (rb & 7)) * 8];
            bf1[i] = *(const f16x8*)&Bs[rb][((4 + quad) ^ (rb & 7)) * 8];
        }
        BAR_LGKM();
        const bool more = (t + 2 < NT);
        if (more) STAGE(asb, bsb, (t + 2) * 64);   // 8 loads, fly 2 iters
        __builtin_amdgcn_s_setprio(1);
        #pragma unroll
        for (int i = 0; i < 4; i++)
            #pragma unroll
            for (int j = 0; j < 4; j++) {
                acc[i][j] = __builtin_amdgcn_mfma_f32_16x16x32_f16(af0[i], bf0[j], acc[i][j], 0, 0, 0);
                acc[i][j] = __builtin_amdgcn_mfma_f32_16x16x32_f16(af1[i], bf1[j], acc[i][j], 0, 0, 0);
            }
        __builtin_amdgcn_s_setprio(0);
        if (more) BAR_VM8(); else BAR_VM0();
    };

    STAGE(a0b, b0b, 0);
    STAGE(a1b, b1b, 64);
    BAR_VM8();               // tile 0 complete for ALL waves; tile 1 in flight

    for (int t = 0; t < NT; t += 2) {
        ITER(As0, Bs0, a0b, b0b, t);
        ITER(As1, Bs1, a1b, b1b, t + 1);
    }

    const int region = (MODE == 1) ? (n0 >> 10) : 0;

    if (MODE == 1 && region == 2) {
        const int b  = m0 >> 11;
        const int s0 = m0 & 2047;
        #pragma unroll
        for (int i = 0; i < 4; i++) {
            #pragma unroll
            for (int j = 0; j < 4; j++) {
                const int nloc = wn * 64 + j * 16 + l16;
                const float bn = bias[n0 + nloc];
                #pragma unroll
                for (int r = 0; r < 4; r++) {
                    const int sloc = wm * 64 + i * 16 + quad * 4 + r;
                    const int sp   = (sloc & ~31) | ((sloc & 15) << 1) | ((sloc >> 4) & 1);
                    const int phys = (sp >> 3) ^ (nloc & 15);
                    smem[nloc * 128 + phys * 8 + (sp & 7)] = (f16)(acc[i][j][r] + bn);
                }
            }
        }
        __syncthreads();
        const int nl = tid >> 1;                 // 0..127 local n
        const int hf = tid & 1;                  // s half
        const int np0 = n0 - 2048;
        f16* dst = vT + ((size_t)(b * 16 + ((np0 + nl) >> 6)) * HD + (nl & 63)) * SEQ
                      + s0 + hf * 64;
        #pragma unroll
        for (int ch = 0; ch < 8; ch++) {
            const int lc   = hf * 8 + ch;
            const int phys = lc ^ (nl & 15);
            const f16x8 v  = *(const f16x8*)&smem[nl * 128 + phys * 8];
            *(f16x8*)(dst + ch * 8) = v;
        }
        return;
    }

    #pragma unroll
    for (int i = 0; i < 4; i++) {
        const int mb = m0 + wm * 64 + i * 16 + quad * 4;
        #pragma unroll
        for (int j = 0; j < 4; j++) {
            const int n  = n0 + wn * 64 + j * 16 + l16;
            const float bn = bias[n];
            #pragma unroll
            for (int r = 0; r < 4; r++) {
                const int m = mb + r;
                const float v = acc[i][j][r] + bn;
                if (MODE == 0) {
                    Cf[(size_t)m * N + n] = v;
                } else {
                    const int b = m >> 11, s = m & 2047;
                    if (region == 0) {
                        qH[(size_t)m * EMBED + n] = (f16)(v * SCALE_Q);
                    } else {   // region 1: K
                        const int np = n - 1024, hh = np >> 6, d = np & 63;
                        kH[(((size_t)(b * 16 + hh) * SEQ + s) << 6) + d] = (f16)v;
                    }
                }
            }
        }
    }
}

// ---------------------------------------------------------------------------
// MFMA flash attention v9: double-buffered K/V with top-of-iter staging.
// Round-8 counters (84.8us, Mfma 41 / VALU 40 / occ 34.5): neither pipe
// saturated -> barrier/drain bound. v8 paid 2 __syncthreads per iter with
// stage->drain distance of only one phase (~300-500cy). v9: stage kb+1 into
// the OTHER (statically named) K/V buffers at the TOP of the iteration ->
// issue-to-drain = one FULL iteration (~1300cy) of QK^T+exp+PV, so the
// single end-of-iter __syncthreads (vmcnt0+lgkm0) is a free drain.
// Barriers: 2/iter -> 1/iter. Overwrite safety: buffers written by the
// top-stage were last read in iter kb-1, retired before its ending barrier.
// Pl shrinks to ONE shared per-wave buffer (v5 pattern: s0 store->read->PV,
// then s1 overwrites; same-wave DS is in-order). LDS 16+16+8 = 40 KB ->
// 4 blocks/CU kept. Cost: vf re-read per s (+8 b128/iter on the LDS pipe).
// Everything else identical (swizzles, raw v_exp, cvt_pkrtz, ones-MFMA ls).
// ---------------------------------------------------------------------------
__global__ __launch_bounds__(256, 4) void attn_mfma(const f16* __restrict__ qH,
                                                    const f16* __restrict__ kH,
                                                    const f16* __restrict__ vT,
                                                    f16* __restrict__ ctx) {
    __shared__ alignas(16) f16 Ks0[64 * 64];       // 8 KB, swizzled [key][dim]
    __shared__ alignas(16) f16 Ks1[64 * 64];       // 8 KB
    __shared__ alignas(16) f16 Vt0[64 * 64];       // 8 KB, swizzled [dim][keycol]
    __shared__ alignas(16) f16 Vt1[64 * 64];       // 8 KB
    __shared__ alignas(16) f16 Pl[4][16 * 64];     // 8 KB, chunk-xor swizzled

    const int tid  = threadIdx.x;
    const int wave = tid >> 6;
    const int lane = tid & 63;
    const int quad = lane >> 4;
    const int l16  = lane & 15;

    const int bid = (int)blockIdx.x;
    const int swz = (bid & 7) * 128 + (bid >> 3);
    const int qb = swz & 15;
    const int bh = swz >> 4;
    const int h  = bh & 15;
    const int b  = bh >> 4;
    const int q0 = qb * 128 + wave * 32;

    const f16* kB = kH + (size_t)bh * SEQ * HD;
    const f16* vB = vT + (size_t)bh * HD * SEQ;

    f16x8 qf[2][2];
    #pragma unroll
    for (int s = 0; s < 2; s++) {
        const f16* qp = qH + (size_t)(b * SEQ + q0 + s * 16 + l16) * EMBED + h * HD;
        #pragma unroll
        for (int c = 0; c < 2; c++)
            qf[s][c] = *(const f16x8*)(qp + c * 32 + quad * 8);
    }

    fx4 o[2][4];
    fx4 ls[2];
    #pragma unroll
    for (int s = 0; s < 2; s++) {
        ls[s] = (fx4){0.f, 0.f, 0.f, 0.f};
        #pragma unroll
        for (int dc = 0; dc < 4; dc++)
            o[s][dc] = (fx4){0.f, 0.f, 0.f, 0.f};
    }

    f16x8 ones8;
    #pragma unroll
    for (int j = 0; j < 8; j++) ones8[j] = (f16)1.0f;

    lds_char* ks0b = (lds_char*)&Ks0[0];
    lds_char* ks1b = (lds_char*)&Ks1[0];
    lds_char* vt0b = (lds_char*)&Vt0[0];
    lds_char* vt1b = (lds_char*)&Vt1[0];

    auto STAGE_K = [&](int kb, lds_char* ksb) {
        #pragma unroll
        for (int it = 0; it < 2; it++) {
            const int g  = wave * 2 + it;
            const int c  = g * 64 + lane;
            const int r  = c >> 3;
            const int jl = (c & 7) ^ (r & 7);
            __builtin_amdgcn_global_load_lds(
                (glb_char*)(kB + (size_t)(kb * 64 + r) * HD + jl * 8),
                ksb + g * 1024, 16, 0, 0);
        }
    };
    auto STAGE_V = [&](int kb, lds_char* vsb) {
        #pragma unroll
        for (int it = 0; it < 2; it++) {
            const int g  = wave * 2 + it;
            const int c  = g * 64 + lane;
            const int r  = c >> 3;
            const int jl = (c & 7) ^ (r & 7);
            __builtin_amdgcn_global_load_lds(
                (glb_char*)(vB + (size_t)r * SEQ + kb * 64 + jl * 8),
                vsb + g * 1024, 16, 0, 0);
        }
    };

    // exp + P store + P read + PV + ls for one qset (st is that qset's score).
    auto PVS = [&](const fx4* st, fx4* osd, fx4& lss, const f16* VtC) {
        #pragma unroll
        for (int g = 0; g < 2; g++)
            #pragma unroll
            for (int r = 0; r < 4; r++) {
                const int row = quad * 4 + r;
                const int cc  = (g * 4 + (l16 >> 2)) ^ (row & 7);
                const float pa = __builtin_amdgcn_exp2f(st[2 * g][r]);
                const float pb = __builtin_amdgcn_exp2f(st[2 * g + 1][r]);
                const f16x2 pk = __builtin_bit_cast(f16x2, __builtin_amdgcn_cvt_pkrtz(pa, pb));
                *(f16x2*)&Pl[wave][row * 64 + cc * 8 + (l16 & 3) * 2] = pk;
            }
        const f16x8 pf0 = *(const f16x8*)&Pl[wave][l16 * 64 + ((0 + quad) ^ (l16 & 7)) * 8];
        const f16x8 pf1 = *(const f16x8*)&Pl[wave][l16 * 64 + ((4 + quad) ^ (l16 & 7)) * 8];
        __builtin_amdgcn_s_setprio(1);
        #pragma unroll
        for (int dc = 0; dc < 4; dc++) {
            const int row = 16 * dc + l16;
            const f16x8 vf0 = *(const f16x8*)&VtC[(row * 8 + ((0 + quad) ^ (row & 7))) * 8];
            const f16x8 vf1 = *(const f16x8*)&VtC[(row * 8 + ((4 + quad) ^ (row & 7))) * 8];
            osd[dc] = __builtin_amdgcn_mfma_f32_16x16x32_f16(pf0, vf0, osd[dc], 0, 0, 0);
            osd[dc] = __builtin_amdgcn_mfma_f32_16x16x32_f16(pf1, vf1, osd[dc], 0, 0, 0);
        }
        lss = __builtin_amdgcn_mfma_f32_16x16x32_f16(pf0, ones8, lss, 0, 0, 0);
        lss = __builtin_amdgcn_mfma_f32_16x16x32_f16(pf1, ones8, lss, 0, 0, 0);
        __builtin_amdgcn_s_setprio(0);
    };

    // One iteration: stage kb+1 into (nks,nvt), compute tile kb from (KsC,VtC).
    auto BODY = [&](const f16* KsC, const f16* VtC,
                    lds_char* nks, lds_char* nvt, int kb) {
        if (kb + 1 < SEQ / 64) {
            STAGE_K(kb + 1, nks);           // in flight across this whole iter
            STAGE_V(kb + 1, nvt);
        }
        // ---- joint QK^T for both qsets (K fragments read once) ----
        fx4 st0[4], st1[4];
        __builtin_amdgcn_s_setprio(1);
        #pragma unroll
        for (int t = 0; t < 4; t++) {
            const int row = l16 + 16 * t;
            const f16x8 kt0 = *(const f16x8*)&KsC[(row * 8 + ((0 + quad) ^ (row & 7))) * 8];
            const f16x8 kt1 = *(const f16x8*)&KsC[(row * 8 + ((4 + quad) ^ (row & 7))) * 8];
            fx4 z = {0.f, 0.f, 0.f, 0.f};
            st0[t] = __builtin_amdgcn_mfma_f32_16x16x32_f16(qf[0][0], kt0, z, 0, 0, 0);
            st0[t] = __builtin_amdgcn_mfma_f32_16x16x32_f16(qf[0][1], kt1, st0[t], 0, 0, 0);
            st1[t] = __builtin_amdgcn_mfma_f32_16x16x32_f16(qf[1][0], kt0, z, 0, 0, 0);
            st1[t] = __builtin_amdgcn_mfma_f32_16x16x32_f16(qf[1][1], kt1, st1[t], 0, 0, 0);
        }
        __builtin_amdgcn_s_setprio(0);
        // ---- per-qset softmax+PV (Pl reused: same-wave DS in-order) ----
        PVS(st0, o[0], ls[0], VtC);
        PVS(st1, o[1], ls[1], VtC);
        // ---- single barrier: drains the staged loads (issued a full iter
        //      ago in program order? no - issued at top, ~1300cy ago) and
        //      ensures all waves done reading KsC/VtC before re-stage. ----
        __syncthreads();
    };

    STAGE_K(0, ks0b);
    STAGE_V(0, vt0b);
    __syncthreads();   // tile 0 staged

    for (int kb = 0; kb < SEQ / 64; kb += 2) {
        BODY(Ks0, Vt0, ks1b, vt1b, kb);
        BODY(Ks1, Vt1, ks0b, vt0b, kb + 1);
    }

    #pragma unroll
    for (int s = 0; s < 2; s++) {
        #pragma unroll
        for (int r = 0; r < 4; r++) {
            const float inv = 1.0f / ls[s][r];
            const int q = q0 + s * 16 + quad * 4 + r;
            f16* dst = ctx + (size_t)(b * SEQ + q) * EMBED + h * HD;
            #pragma unroll
            for (int dc = 0; dc < 4; dc++)
                dst[dc * 16 + l16] = (f16)(o[s][dc][r] * inv);
        }
    }
}

// ---------------------------------------------------------------------------
extern "C" void kernel_launch(void* const* d_in, const int* in_sizes, int n_in,
                              void* d_out, int out_size, void* d_ws, size_t ws_size,
                              hipStream_t stream) {
    const float* x     = (const float*)d_in[0];
    const float* Wqkv  = (const float*)d_in[1];
    const float* bqkv  = (const float*)d_in[2];
    const float* Wproj = (const float*)d_in[3];
    const float* bproj = (const float*)d_in[4];
    float* out = (float*)d_out;

    f16* x_h = (f16*)d_ws;                          // 8M
    f16* qHb = x_h + (size_t)ROWS * EMBED;          // 8M
    f16* kHb = qHb + (size_t)ROWS * EMBED;          // 8M
    f16* vTb = kHb + (size_t)ROWS * EMBED;          // 8M
    f16* ctx = vTb + (size_t)ROWS * EMBED;          // 8M
    f16* Wqt = ctx + (size_t)ROWS * EMBED;          // 3M
    f16* Wpt = Wqt + (size_t)3 * EMBED * EMBED;     // 1M

    // 0) fused conversions (x, Wqkv^T, Wproj^T)
    prep<<<dim3(12288), dim3(256), 0, stream>>>(x, x_h, Wqkv, Wqt, Wproj, Wpt);

    // 1) qkv GEMM (BM=128): grid (24, 64) = 1536 blocks
    gemm_f16k<1><<<dim3(3 * EMBED / 128, ROWS / 128), dim3(256), 0, stream>>>(
        x_h, Wqt, bqkv, nullptr, qHb, kHb, vTb, ROWS, 3 * EMBED, EMBED);

    // 2) flash attention
    attn_mfma<<<dim3(64 * 16), dim3(256), 0, stream>>>(qHb, kHb, vTb, ctx);

    // 3) out = ctx @ Wproj + bias (BM=128): grid (8, 64) = 512 blocks
    gemm_f16k<0><<<dim3(EMBED / 128, ROWS / 128), dim3(256), 0, stream>>>(
        ctx, Wpt, bproj, out, nullptr, nullptr, nullptr, ROWS, EMBED, EMBED);
}

// Round 10
// 256.856 us; speedup vs baseline: 1.3445x; 1.3445x over previous
//
#include <hip/hip_runtime.h>
#include <math.h>

#define EMBED 1024
#define HEADS 16
#define HD    64
#define SEQ   2048
#define BATCH 4
#define ROWS  (BATCH * SEQ)   // 8192

typedef _Float16 f16;
typedef __attribute__((ext_vector_type(8))) _Float16 f16x8;
typedef __attribute__((ext_vector_type(4))) _Float16 f16x4;
typedef __attribute__((ext_vector_type(2))) _Float16 f16x2;
typedef __attribute__((ext_vector_type(4))) float    fx4;

typedef __attribute__((address_space(3))) char  lds_char;
typedef __attribute__((address_space(1))) const char glb_char;

#define SCALE_Q 0.18033688011112042f   // 0.125 * log2(e), folded into Q at GEMM1

// Raw barrier + counted waits (GEMM): __syncthreads() emits vmcnt(0) and
// would drain the stage-ahead pipeline every tile.
#define BAR_LGKM()  asm volatile("s_waitcnt lgkmcnt(0)\n\ts_barrier" ::: "memory")
#define BAR_VM8()   asm volatile("s_waitcnt vmcnt(8)\n\ts_barrier" ::: "memory")
#define BAR_VM6()   asm volatile("s_waitcnt vmcnt(6)\n\ts_barrier" ::: "memory")
#define BAR_VM0()   asm volatile("s_waitcnt vmcnt(0)\n\ts_barrier" ::: "memory")

// ---------------------------------------------------------------------------
// Fused prep (unchanged).
// ---------------------------------------------------------------------------
__global__ __launch_bounds__(256) void prep(const float* __restrict__ x,
                                            f16* __restrict__ x_h,
                                            const float* __restrict__ Wqkv,
                                            f16* __restrict__ Wqt,
                                            const float* __restrict__ Wproj,
                                            f16* __restrict__ Wpt) {
    const int blk = blockIdx.x;
    if (blk < 8192) {
        const int i = (blk * 256 + threadIdx.x) * 4;
        const float4 v = *(const float4*)(x + i);
        f16x4 o = {(f16)v.x, (f16)v.y, (f16)v.z, (f16)v.w};
        *(f16x4*)(x_h + i) = o;
        return;
    }
    __shared__ float t[32][33];
    const float* W;
    f16* Wt;
    int N, bx, by;
    if (blk < 8192 + 3072) {
        const int b2 = blk - 8192;
        W = Wqkv; Wt = Wqt; N = 3072; bx = b2 % 96; by = b2 / 96;
    } else {
        const int b2 = blk - 8192 - 3072;
        W = Wproj; Wt = Wpt; N = 1024; bx = b2 % 32; by = b2 / 32;
    }
    const int tx = threadIdx.x & 31, ty = threadIdx.x >> 5;   // 32 x 8
    const int k0 = by * 32, n0 = bx * 32;
    #pragma unroll
    for (int i = 0; i < 4; i++)
        t[ty + i * 8][tx] = W[(size_t)(k0 + ty + i * 8) * N + n0 + tx];
    __syncthreads();
    #pragma unroll
    for (int i = 0; i < 4; i++)
        Wt[(size_t)(n0 + ty + i * 8) * 1024 + k0 + tx] = (f16)t[tx][ty + i * 8];
}

// ---------------------------------------------------------------------------
// f16 MFMA GEMM v5: counted-vmcnt double-buffered pipeline (T3+T4), now with
// mode-sized tiles.
// Round-8/9 budget: gemm0 (BM=128, 512 blocks = 2/CU) was ~80us for 1/3 of
// gemm1's FLOPs -> TLP-starved. MODE 0 now BM=64 (MI=2): grid (8,128) =
// 1024 blocks, LDS 48 KB -> 3 blocks/CU. Stage = 6 VMEM/wave -> vmcnt(6).
// MODE 1 unchanged (BM=128, stage 8 VMEM -> vmcnt(8)).
// Per iter: ds_read frags -> lgkmcnt(0)+barrier (NO vm drain) -> STAGE(t+2)
// -> MFMA under setprio -> vmcnt(N)+barrier. BK=64 + chunk-XOR swizzle.
// ---------------------------------------------------------------------------
template <int MODE>
__global__ __launch_bounds__(256) void gemm_f16k(const f16* __restrict__ A,
                                                 const f16* __restrict__ Bt,
                                                 const float* __restrict__ bias,
                                                 float* __restrict__ Cf,
                                                 f16* __restrict__ qH,
                                                 f16* __restrict__ kH,
                                                 f16* __restrict__ vT,
                                                 int M, int N, int K) {
    constexpr int MI  = (MODE == 0) ? 2 : 4;            // acc rows per wave
    constexpr int BM  = MI * 32;                        // 64 or 128
    constexpr int AEL = BM * 64;                        // As f16 per buffer
    constexpr int BEL = 128 * 64;                       // Bs f16 per buffer
    __shared__ alignas(16) f16 smem[2 * (AEL + BEL)];   // 48 KB / 64 KB

    f16 (*As0)[64] = (f16(*)[64])(smem);
    f16 (*As1)[64] = (f16(*)[64])(smem + AEL);
    f16 (*Bs0)[64] = (f16(*)[64])(smem + 2 * AEL);
    f16 (*Bs1)[64] = (f16(*)[64])(smem + 2 * AEL + BEL);
    lds_char* a0b = (lds_char*)smem;
    lds_char* a1b = (lds_char*)smem + 2 * AEL;          // bytes
    lds_char* b0b = (lds_char*)smem + 4 * AEL;
    lds_char* b1b = (lds_char*)smem + 4 * AEL + 2 * BEL;

    const int tid  = threadIdx.x;
    const int wave = tid >> 6;
    const int lane = tid & 63;
    const int quad = lane >> 4;
    const int l16  = lane & 15;

    // XCD-aware bijective chunk swizzle (nwg % 8 == 0 at both call sites).
    const int nwg  = gridDim.x * gridDim.y;
    const int flat = blockIdx.y * gridDim.x + blockIdx.x;
    const int swz  = (flat & 7) * (nwg >> 3) + (flat >> 3);
    const int bx   = swz % gridDim.x;
    const int by   = swz / gridDim.x;
    const int m0   = by * BM;
    const int n0   = bx * 128;
    const int wm   = wave & 1;
    const int wn   = wave >> 1;

    fx4 acc[MI][4];
    #pragma unroll
    for (int i = 0; i < MI; i++)
        #pragma unroll
        for (int j = 0; j < 4; j++)
            acc[i][j] = (fx4){0.f, 0.f, 0.f, 0.f};

    // Staging: group g covers 8 rows (1 KB); lane's 16B land at row
    // g*8 + (lane>>3), physical chunk lane&7. Source k-chunk = phys ^ (row&7)
    // -> swizzle lives in the per-lane GLOBAL address; LDS dest linear.
    const int srow = lane >> 3;
    const int sjl  = ((lane & 7) ^ (srow & 7)) * 8;     // f16 offset
    auto STAGE = [&](lds_char* asb, lds_char* bsb, int k0) {
        // A: BM/8 groups (MI==2 -> 8 groups, 2/wave; MI==4 -> 16, 4/wave)
        #pragma unroll
        for (int it = 0; it < MI; it++) {
            const int g = it * 4 + wave;
            const int r = g * 8 + srow;
            __builtin_amdgcn_global_load_lds(
                (glb_char*)(A + (size_t)(m0 + r) * K + k0 + sjl),
                asb + g * 1024, 16, 0, 0);
        }
        #pragma unroll
        for (int it = 0; it < 4; it++) {
            const int g = it * 4 + wave;
            const int r = g * 8 + srow;
            __builtin_amdgcn_global_load_lds(
                (glb_char*)(Bt + (size_t)(n0 + r) * K + k0 + sjl),
                bsb + g * 1024, 16, 0, 0);
        }
    };

    const int NT = K >> 6;   // 16

    auto ITER = [&](f16 (*As)[64], f16 (*Bs)[64],
                    lds_char* asb, lds_char* bsb, int t) {
        f16x8 af0[MI], af1[MI], bf0[4], bf1[4];
        #pragma unroll
        for (int i = 0; i < MI; i++) {
            const int ra = wm * (MI * 16) + i * 16 + l16;
            af0[i] = *(const f16x8*)&As[ra][((0 + quad) ^ (ra & 7)) * 8];
            af1[i] = *(const f16x8*)&As[ra][((4 + quad) ^ (ra & 7)) * 8];
        }
        #pragma unroll
        for (int j = 0; j < 4; j++) {
            const int rb = wn * 64 + j * 16 + l16;
            bf0[j] = *(const f16x8*)&Bs[rb][((0 + quad) ^ (rb & 7)) * 8];
            bf1[j] = *(const f16x8*)&Bs[rb][((4 + quad) ^ (rb & 7)) * 8];
        }
        BAR_LGKM();
        const bool more = (t + 2 < NT);
        if (more) STAGE(asb, bsb, (t + 2) * 64);   // loads fly 2 iters
        __builtin_amdgcn_s_setprio(1);
        #pragma unroll
        for (int i = 0; i < MI; i++)
            #pragma unroll
            for (int j = 0; j < 4; j++) {
                acc[i][j] = __builtin_amdgcn_mfma_f32_16x16x32_f16(af0[i], bf0[j], acc[i][j], 0, 0, 0);
                acc[i][j] = __builtin_amdgcn_mfma_f32_16x16x32_f16(af1[i], bf1[j], acc[i][j], 0, 0, 0);
            }
        __builtin_amdgcn_s_setprio(0);
        // completes tile t+1's loads; t+2's stay in flight.
        if (more) { if constexpr (MODE == 0) BAR_VM6(); else BAR_VM8(); }
        else      BAR_VM0();
    };

    STAGE(a0b, b0b, 0);
    STAGE(a1b, b1b, 64);
    if constexpr (MODE == 0) BAR_VM6(); else BAR_VM8();   // tile 0 ready

    for (int t = 0; t < NT; t += 2) {
        ITER(As0, Bs0, a0b, b0b, t);
        ITER(As1, Bs1, a1b, b1b, t + 1);
    }

    const int region = (MODE == 1) ? (n0 >> 10) : 0;

    if (MODE == 1 && region == 2) {
        // ---- V epilogue via LDS bounce (block-uniform branch, verified) ----
        const int b  = m0 >> 11;
        const int s0 = m0 & 2047;
        #pragma unroll
        for (int i = 0; i < MI; i++) {
            #pragma unroll
            for (int j = 0; j < 4; j++) {
                const int nloc = wn * 64 + j * 16 + l16;
                const float bn = bias[n0 + nloc];
                #pragma unroll
                for (int r = 0; r < 4; r++) {
                    const int sloc = wm * 64 + i * 16 + quad * 4 + r;
                    const int sp   = (sloc & ~31) | ((sloc & 15) << 1) | ((sloc >> 4) & 1);
                    const int phys = (sp >> 3) ^ (nloc & 15);
                    smem[nloc * 128 + phys * 8 + (sp & 7)] = (f16)(acc[i][j][r] + bn);
                }
            }
        }
        __syncthreads();
        const int nl = tid >> 1;                 // 0..127 local n
        const int hf = tid & 1;                  // s half
        const int np0 = n0 - 2048;
        f16* dst = vT + ((size_t)(b * 16 + ((np0 + nl) >> 6)) * HD + (nl & 63)) * SEQ
                      + s0 + hf * 64;
        #pragma unroll
        for (int ch = 0; ch < 8; ch++) {
            const int lc   = hf * 8 + ch;
            const int phys = lc ^ (nl & 15);
            const f16x8 v  = *(const f16x8*)&smem[nl * 128 + phys * 8];
            *(f16x8*)(dst + ch * 8) = v;
        }
        return;
    }

    #pragma unroll
    for (int i = 0; i < MI; i++) {
        const int mb = m0 + wm * (MI * 16) + i * 16 + quad * 4;
        #pragma unroll
        for (int j = 0; j < 4; j++) {
            const int n  = n0 + wn * 64 + j * 16 + l16;
            const float bn = bias[n];
            #pragma unroll
            for (int r = 0; r < 4; r++) {
                const int m = mb + r;
                const float v = acc[i][j][r] + bn;
                if (MODE == 0) {
                    Cf[(size_t)m * N + n] = v;
                } else {
                    const int b = m >> 11, s = m & 2047;
                    if (region == 0) {
                        qH[(size_t)m * EMBED + n] = (f16)(v * SCALE_Q);
                    } else {   // region 1: K
                        const int np = n - 1024, hh = np >> 6, d = np & 63;
                        kH[(((size_t)(b * 16 + hh) * SEQ + s) << 6) + d] = (f16)v;
                    }
                }
            }
        }
    }
}

// ---------------------------------------------------------------------------
// MFMA flash attention v8 (REVERTED to round-8 exact source; 84.8us verified).
// Round-9 lesson: double-buffered deep prefetch broke the temporal alignment
// of the 16 query-blocks sharing each (b,h)'s K/V -> per-XCD L2 working set
// blew past 4 MB, FETCH 25->152 MB, 2x slower. The 2-barrier lockstep here
// is load-bearing for L2 reuse. Do not deepen this pipeline.
// ---------------------------------------------------------------------------
__global__ __launch_bounds__(256, 4) void attn_mfma(const f16* __restrict__ qH,
                                                    const f16* __restrict__ kH,
                                                    const f16* __restrict__ vT,
                                                    f16* __restrict__ ctx) {
    __shared__ alignas(16) f16 Ks[64 * 64];        // 8 KB, swizzled [key][dim]
    __shared__ alignas(16) f16 Vt[64 * 64];        // 8 KB, swizzled [dim][keycol]
    __shared__ alignas(16) f16 Pl[4][2][16 * 64];  // 16 KB, chunk-xor swizzled

    const int tid  = threadIdx.x;
    const int wave = tid >> 6;
    const int lane = tid & 63;
    const int quad = lane >> 4;
    const int l16  = lane & 15;

    const int bid = (int)blockIdx.x;
    const int swz = (bid & 7) * 128 + (bid >> 3);
    const int qb = swz & 15;
    const int bh = swz >> 4;
    const int h  = bh & 15;
    const int b  = bh >> 4;
    const int q0 = qb * 128 + wave * 32;

    const f16* kB = kH + (size_t)bh * SEQ * HD;
    const f16* vB = vT + (size_t)bh * HD * SEQ;

    f16x8 qf[2][2];
    #pragma unroll
    for (int s = 0; s < 2; s++) {
        const f16* qp = qH + (size_t)(b * SEQ + q0 + s * 16 + l16) * EMBED + h * HD;
        #pragma unroll
        for (int c = 0; c < 2; c++)
            qf[s][c] = *(const f16x8*)(qp + c * 32 + quad * 8);
    }

    fx4 o[2][4];
    fx4 ls[2];
    #pragma unroll
    for (int s = 0; s < 2; s++) {
        ls[s] = (fx4){0.f, 0.f, 0.f, 0.f};
        #pragma unroll
        for (int dc = 0; dc < 4; dc++)
            o[s][dc] = (fx4){0.f, 0.f, 0.f, 0.f};
    }

    f16x8 ones8;
    #pragma unroll
    for (int j = 0; j < 8; j++) ones8[j] = (f16)1.0f;

    lds_char* ksb = (lds_char*)&Ks[0];
    lds_char* vsb = (lds_char*)&Vt[0];

    auto STAGE_K = [&](int kb) {
        #pragma unroll
        for (int it = 0; it < 2; it++) {
            const int g  = wave * 2 + it;
            const int c  = g * 64 + lane;
            const int r  = c >> 3;
            const int jl = (c & 7) ^ (r & 7);
            __builtin_amdgcn_global_load_lds(
                (glb_char*)(kB + (size_t)(kb * 64 + r) * HD + jl * 8),
                ksb + g * 1024, 16, 0, 0);
        }
    };
    auto STAGE_V = [&](int kb) {
        #pragma unroll
        for (int it = 0; it < 2; it++) {
            const int g  = wave * 2 + it;
            const int c  = g * 64 + lane;
            const int r  = c >> 3;
            const int jl = (c & 7) ^ (r & 7);
            __builtin_amdgcn_global_load_lds(
                (glb_char*)(vB + (size_t)r * SEQ + kb * 64 + jl * 8),
                vsb + g * 1024, 16, 0, 0);
        }
    };

    STAGE_K(0);
    STAGE_V(0);
    __syncthreads();

    for (int kb = 0; kb < SEQ / 64; kb++) {
        fx4 st0[4], st1[4];
        __builtin_amdgcn_s_setprio(1);
        #pragma unroll
        for (int t = 0; t < 4; t++) {
            const int row = l16 + 16 * t;
            const f16x8 kt0 = *(const f16x8*)&Ks[(row * 8 + ((0 + quad) ^ (row & 7))) * 8];
            const f16x8 kt1 = *(const f16x8*)&Ks[(row * 8 + ((4 + quad) ^ (row & 7))) * 8];
            fx4 z = {0.f, 0.f, 0.f, 0.f};
            st0[t] = __builtin_amdgcn_mfma_f32_16x16x32_f16(qf[0][0], kt0, z, 0, 0, 0);
            st0[t] = __builtin_amdgcn_mfma_f32_16x16x32_f16(qf[0][1], kt1, st0[t], 0, 0, 0);
            st1[t] = __builtin_amdgcn_mfma_f32_16x16x32_f16(qf[1][0], kt0, z, 0, 0, 0);
            st1[t] = __builtin_amdgcn_mfma_f32_16x16x32_f16(qf[1][1], kt1, st1[t], 0, 0, 0);
        }
        __builtin_amdgcn_s_setprio(0);

        #pragma unroll
        for (int g = 0; g < 2; g++)
            #pragma unroll
            for (int r = 0; r < 4; r++) {
                const int row = quad * 4 + r;
                const int cc  = (g * 4 + (l16 >> 2)) ^ (row & 7);
                {
                    const float pa = __builtin_amdgcn_exp2f(st0[2 * g][r]);
                    const float pb = __builtin_amdgcn_exp2f(st0[2 * g + 1][r]);
                    const f16x2 pk = __builtin_bit_cast(f16x2, __builtin_amdgcn_cvt_pkrtz(pa, pb));
                    *(f16x2*)&Pl[wave][0][row * 64 + cc * 8 + (l16 & 3) * 2] = pk;
                }
                {
                    const float pa = __builtin_amdgcn_exp2f(st1[2 * g][r]);
                    const float pb = __builtin_amdgcn_exp2f(st1[2 * g + 1][r]);
                    const f16x2 pk = __builtin_bit_cast(f16x2, __builtin_amdgcn_cvt_pkrtz(pa, pb));
                    *(f16x2*)&Pl[wave][1][row * 64 + cc * 8 + (l16 & 3) * 2] = pk;
                }
            }

        __syncthreads();
        if (kb + 1 < SEQ / 64) STAGE_K(kb + 1);

        const f16x8 pf00 = *(const f16x8*)&Pl[wave][0][l16 * 64 + ((0 + quad) ^ (l16 & 7)) * 8];
        const f16x8 pf01 = *(const f16x8*)&Pl[wave][0][l16 * 64 + ((4 + quad) ^ (l16 & 7)) * 8];
        const f16x8 pf10 = *(const f16x8*)&Pl[wave][1][l16 * 64 + ((0 + quad) ^ (l16 & 7)) * 8];
        const f16x8 pf11 = *(const f16x8*)&Pl[wave][1][l16 * 64 + ((4 + quad) ^ (l16 & 7)) * 8];
        __builtin_amdgcn_s_setprio(1);
        #pragma unroll
        for (int dc = 0; dc < 4; dc++) {
            const int row = 16 * dc + l16;
            const f16x8 vf0 = *(const f16x8*)&Vt[(row * 8 + ((0 + quad) ^ (row & 7))) * 8];
            const f16x8 vf1 = *(const f16x8*)&Vt[(row * 8 + ((4 + quad) ^ (row & 7))) * 8];
            o[0][dc] = __builtin_amdgcn_mfma_f32_16x16x32_f16(pf00, vf0, o[0][dc], 0, 0, 0);
            o[0][dc] = __builtin_amdgcn_mfma_f32_16x16x32_f16(pf01, vf1, o[0][dc], 0, 0, 0);
            o[1][dc] = __builtin_amdgcn_mfma_f32_16x16x32_f16(pf10, vf0, o[1][dc], 0, 0, 0);
            o[1][dc] = __builtin_amdgcn_mfma_f32_16x16x32_f16(pf11, vf1, o[1][dc], 0, 0, 0);
        }
        ls[0] = __builtin_amdgcn_mfma_f32_16x16x32_f16(pf00, ones8, ls[0], 0, 0, 0);
        ls[0] = __builtin_amdgcn_mfma_f32_16x16x32_f16(pf01, ones8, ls[0], 0, 0, 0);
        ls[1] = __builtin_amdgcn_mfma_f32_16x16x32_f16(pf10, ones8, ls[1], 0, 0, 0);
        ls[1] = __builtin_amdgcn_mfma_f32_16x16x32_f16(pf11, ones8, ls[1], 0, 0, 0);
        __builtin_amdgcn_s_setprio(0);

        __syncthreads();
        if (kb + 1 < SEQ / 64) STAGE_V(kb + 1);
    }

    #pragma unroll
    for (int s = 0; s < 2; s++) {
        #pragma unroll
        for (int r = 0; r < 4; r++) {
            const float inv = 1.0f / ls[s][r];
            const int q = q0 + s * 16 + quad * 4 + r;
            f16* dst = ctx + (size_t)(b * SEQ + q) * EMBED + h * HD;
            #pragma unroll
            for (int dc = 0; dc < 4; dc++)
                dst[dc * 16 + l16] = (f16)(o[s][dc][r] * inv);
        }
    }
}

// ---------------------------------------------------------------------------
extern "C" void kernel_launch(void* const* d_in, const int* in_sizes, int n_in,
                              void* d_out, int out_size, void* d_ws, size_t ws_size,
                              hipStream_t stream) {
    const float* x     = (const float*)d_in[0];
    const float* Wqkv  = (const float*)d_in[1];
    const float* bqkv  = (const float*)d_in[2];
    const float* Wproj = (const float*)d_in[3];
    const float* bproj = (const float*)d_in[4];
    float* out = (float*)d_out;

    f16* x_h = (f16*)d_ws;                          // 8M
    f16* qHb = x_h + (size_t)ROWS * EMBED;          // 8M
    f16* kHb = qHb + (size_t)ROWS * EMBED;          // 8M
    f16* vTb = kHb + (size_t)ROWS * EMBED;          // 8M
    f16* ctx = vTb + (size_t)ROWS * EMBED;          // 8M
    f16* Wqt = ctx + (size_t)ROWS * EMBED;          // 3M
    f16* Wpt = Wqt + (size_t)3 * EMBED * EMBED;     // 1M

    // 0) fused conversions (x, Wqkv^T, Wproj^T)
    prep<<<dim3(12288), dim3(256), 0, stream>>>(x, x_h, Wqkv, Wqt, Wproj, Wpt);

    // 1) qkv GEMM (BM=128): grid (24, 64) = 1536 blocks
    gemm_f16k<1><<<dim3(3 * EMBED / 128, ROWS / 128), dim3(256), 0, stream>>>(
        x_h, Wqt, bqkv, nullptr, qHb, kHb, vTb, ROWS, 3 * EMBED, EMBED);

    // 2) flash attention
    attn_mfma<<<dim3(64 * 16), dim3(256), 0, stream>>>(qHb, kHb, vTb, ctx);

    // 3) out = ctx @ Wproj + bias (BM=64): grid (8, 128) = 1024 blocks
    gemm_f16k<0><<<dim3(EMBED / 128, ROWS / 64), dim3(256), 0, stream>>>(
        ctx, Wpt, bproj, out, nullptr, nullptr, nullptr, ROWS, EMBED, EMBED);
}